// Round 5
// baseline (440.432 us; speedup 1.0000x reference)
//
#include <hip/hip_runtime.h>
#include <math.h>

typedef _Float16 f16;
typedef _Float16 f16x2 __attribute__((ext_vector_type(2)));
typedef _Float16 f16x8 __attribute__((ext_vector_type(8)));
typedef float f32x4 __attribute__((ext_vector_type(4)));

#define NB 16
#define SS 2048
#define DD 512

// async global->LDS, 16B per lane; LDS dst = wave-uniform base + lane*16B
__device__ __forceinline__ void gl_lds16(const void* g, void* l) {
  __builtin_amdgcn_global_load_lds(
      (const __attribute__((address_space(1))) unsigned int*)g,
      (__attribute__((address_space(3))) unsigned int*)l, 16, 0, 0);
}

// pack two f32 -> f16x2 word
__device__ __forceinline__ int pk2(float a, float b) {
  f16x2 t = {(f16)a, (f16)b};
  return __builtin_bit_cast(int, t);
}

// ---------------- cast x (fp32) -> fp16, 8 elems/thread ----------------
__global__ __launch_bounds__(256) void cast_kernel(const float* __restrict__ x,
                                                   f16* __restrict__ o) {
  size_t i = (size_t)blockIdx.x * 256 + threadIdx.x;
  const float4* p = (const float4*)x + i * 2;
  float4 a = p[0], b = p[1];
  f16x8 v = {(f16)a.x, (f16)a.y, (f16)a.z, (f16)a.w,
             (f16)b.x, (f16)b.y, (f16)b.z, (f16)b.w};
  *((f16x8*)o + i) = v;
}

// ---------------- transpose 512x512 weights, fp32 -> fp16, z picks matrix ----
__global__ __launch_bounds__(256) void transpose_kernel(
    const float* __restrict__ W0, const float* __restrict__ W1,
    const float* __restrict__ W2, f16* __restrict__ T0, f16* __restrict__ T1,
    f16* __restrict__ T2) {
  const float* W = (blockIdx.z == 0) ? W0 : (blockIdx.z == 1) ? W1 : W2;
  f16* Wt = (blockIdx.z == 0) ? T0 : (blockIdx.z == 1) ? T1 : T2;
  __shared__ float t[32][33];
  int bx = blockIdx.x * 32, by = blockIdx.y * 32;
  int c = threadIdx.x & 31, r0 = threadIdx.x >> 5;
  for (int r = r0; r < 32; r += 8) t[r][c] = W[(size_t)(by + r) * DD + bx + c];
  __syncthreads();
  for (int r = r0; r < 32; r += 8) Wt[(size_t)(bx + r) * DD + by + c] = (f16)t[c][r];
}

// ---------------- fused QKV GEMM (R7 config: fused 128x128, dbuf) ----------
__global__ __launch_bounds__(256) void gemm3_kernel(
    const f16* __restrict__ xh, const f16* __restrict__ WqT,
    const f16* __restrict__ WkT, const f16* __restrict__ WvT,
    f16* __restrict__ Qh, f16* __restrict__ Kh, f16* __restrict__ Vth,
    const float* __restrict__ bq, const float* __restrict__ bk,
    const float* __restrict__ bv) {
  const int wid = (blockIdx.x & 7) * 384 + (blockIdx.x >> 3);  // bijective XCD swz
  const f16* A;
  const f16* Bt;
  f16* C;
  const float* bias;
  int m0, n0, ldc, bias_row;
  float scale;
  if (wid < 2048) {  // Q (0..1023) / K (1024..2047)
    const bool isK = wid >= 1024;
    const int r = wid & 1023;
    A = xh;
    Bt = isK ? WkT : WqT;
    C = isK ? Kh : Qh;
    bias = isK ? bk : bq;
    m0 = (r >> 2) * 128;
    n0 = (r & 3) * 128;
    ldc = DD;
    bias_row = 0;
    scale = isK ? 1.0f : 0.125f;  // fold 1/sqrt(64) into Q
  } else {  // V^T per batch: C[512][2048] = WvT * xh_b^T
    const int v = wid - 2048;
    const int bz = v >> 6, xy = v & 63;
    A = WvT;
    Bt = xh + (size_t)bz * SS * DD;
    C = Vth + (size_t)bz * (size_t)DD * SS;
    bias = bv;
    m0 = ((xy >> 4) & 3) * 128;
    n0 = (xy & 15) * 128;
    ldc = SS;
    bias_row = 1;
    scale = 1.0f;
  }
  __shared__ f16 Ash[2][128 * 32];
  __shared__ f16 Bsh[2][128 * 32];
  const int tid = threadIdx.x, lane = tid & 63, wave = tid >> 6;
  const int wm = wave & 1, wn = wave >> 1;
  const int l15 = lane & 15, lq = lane >> 4;
  f32x4 acc[4][4] = {};
  const int srow = tid >> 2, part = tid & 3;
  const f16* gA = A + (size_t)(m0 + srow) * DD + part * 8;
  const f16* gB = Bt + (size_t)(n0 + srow) * DD + part * 8;
  auto stage = [&](int sb, int kt) {
    f16* lA = &Ash[sb][tid * 8];
    f16* lB = &Bsh[sb][tid * 8];
    gl_lds16(gA + kt * 32, lA);
    gl_lds16(gA + 64 * DD + kt * 32, lA + 2048);
    gl_lds16(gB + kt * 32, lB);
    gl_lds16(gB + 64 * DD + kt * 32, lB + 2048);
  };
  stage(0, 0);
  __syncthreads();
  for (int kt = 0; kt < 16; ++kt) {
    const int buf = kt & 1;
    if (kt < 15) stage(buf ^ 1, kt + 1);
    f16x8 af[4], bf[4];
#pragma unroll
    for (int i = 0; i < 4; ++i)
      af[i] = *(const f16x8*)&Ash[buf][(64 * wm + 16 * i + l15) * 32 + lq * 8];
#pragma unroll
    for (int j = 0; j < 4; ++j)
      bf[j] = *(const f16x8*)&Bsh[buf][(64 * wn + 16 * j + l15) * 32 + lq * 8];
#pragma unroll
    for (int i = 0; i < 4; ++i)
#pragma unroll
      for (int j = 0; j < 4; ++j)
        acc[i][j] = __builtin_amdgcn_mfma_f32_16x16x32_f16(af[i], bf[j], acc[i][j], 0, 0, 0);
    __syncthreads();
  }
#pragma unroll
  for (int i = 0; i < 4; ++i) {
    int rb = 64 * wm + 16 * i + lq * 4;
#pragma unroll
    for (int j = 0; j < 4; ++j) {
      int cc = n0 + 64 * wn + 16 * j + l15;
#pragma unroll
      for (int r = 0; r < 4; ++r) {
        int rr = m0 + rb + r;
        float bv = bias_row ? bias[rr] : bias[cc];
        C[(size_t)rr * ldc + cc] = (f16)((acc[i][j][r] + bv) * scale);
      }
    }
  }
}

// ---------------- flash attention, R9: D-partitioned PV ----------------
// R8 analysis: LDS bytes/iter/CU = K 256KB + V 256KB + DMA 64KB; the V term
// is 8x wave-duplicated (every wave reads ALL of V for its 16 q-rows).
// R9: wave w owns output D-slice [64w..64w+64) for ALL 128 q-rows; P is
// shared via LDS in exact A-frag layout (producer lane L writes its pa at
// Pash[w][L*16B]; consumer lane L reads the same offset -> fragment identity,
// no relayout). V-reads 256->32KB; P adds 8W+64R KB -> ~424KB/iter (0.73x).
// Softmax stays wave-local (swapped QK, defer-max); cross-wave rescale via
// alsh[16/wave] + per-wave trigger flags (triggers ~iter 0 only).
// Sync: mid-iter barrier is LGKM-ONLY (pa/alsh visibility; no vmcnt drain so
// the K/V prefetch DMA keeps flying); end-of-iter __syncthreads() is the
// full drain protecting the double buffers (R6-proven placement).
__global__ __launch_bounds__(512, 2) void attn_kernel(
    const f16* __restrict__ Q, const f16* __restrict__ K,
    const f16* __restrict__ Vt, float* __restrict__ out) {
  const int id = blockIdx.x;
  const int b = (id & 7) + ((id >> 7) << 3);  // XCD x gets batches {x, x+8}
  const int qt = (id >> 3) & 15;
  const int tid = threadIdx.x, lane = tid & 63, wave = tid >> 6;
  const int l15 = lane & 15, lq = lane >> 4;

  __shared__ __align__(16) f16 Kl[2][32][520];  // [key][d], 1040B rows
  __shared__ __align__(16) f16 Vl[2][512][32];  // [e][key], XOR-swizzled quarters
  __shared__ __align__(16) f16 Pash[8][512];    // per-wave P in A-frag order
  __shared__ __align__(16) float alsh[128];     // rescale factors [tile*16 + q]
  __shared__ __align__(16) int flg[8];          // per-wave trigger flags

  const f16* qp = Q + ((size_t)(b * SS + qt * 128 + wave * 16 + l15)) * DD + lq * 8;
  f16x8 qf[16];
#pragma unroll
  for (int kk = 0; kk < 16; ++kk) qf[kk] = *(const f16x8*)(qp + kk * 32);

  const f16* Kb = K + (size_t)b * SS * DD;   // [key][d]
  const f16* Vb = Vt + (size_t)b * DD * SS;  // [e][s]

  const int sdata = (lane & 3) ^ ((lane >> 3) & 3);
  const int vrow = lane >> 2;
  const int vs_off = (lq ^ ((l15 >> 1) & 3)) * 8;

  f16x8 onef;
#pragma unroll
  for (int j = 0; j < 8; ++j) onef[j] = (f16)1.0f;

  auto stage = [&](int sb, int kb) {
#pragma unroll
    for (int rr = 0; rr < 4; ++rr) {
      int row = wave * 4 + rr;
      gl_lds16(Kb + ((size_t)(kb + row)) * DD + lane * 8, &Kl[sb][row][lane * 8]);
    }
#pragma unroll
    for (int i = 0; i < 4; ++i) {
      int e0 = wave * 64 + i * 16;
      gl_lds16(Vb + (size_t)(e0 + vrow) * SS + kb + sdata * 8,
               (f16*)&Vl[sb][e0][0] + lane * 8);
    }
  };

  stage(0, 0);
  __syncthreads();

  f32x4 acco[8][4] = {};  // [q-tile][d-subtile of own 64-col slice]
  f32x4 accl = {};        // own-tile row sums (ones-MFMA)
  float m = -1e30f;       // running max for own q = l15

  for (int it = 0; it < 64; ++it) {
    const int buf = it & 1;
    if (it < 63) stage(buf ^ 1, (it + 1) * 32);
    // ---- QK^T (swapped): keys in regs, q = l15 col ----
    f32x4 sa0 = {}, sa1 = {};
#pragma unroll
    for (int kk = 0; kk < 16; ++kk) {
      f16x8 b0 = *(const f16x8*)&Kl[buf][l15][kk * 32 + lq * 8];
      f16x8 b1 = *(const f16x8*)&Kl[buf][16 + l15][kk * 32 + lq * 8];
      sa0 = __builtin_amdgcn_mfma_f32_16x16x32_f16(b0, qf[kk], sa0, 0, 0, 0);
      sa1 = __builtin_amdgcn_mfma_f32_16x16x32_f16(b1, qf[kk], sa1, 0, 0, 0);
    }
    // ---- defer-max; publish al + flag on trigger ----
    float lm = fmaxf(fmaxf(fmaxf(sa0[0], sa0[1]), fmaxf(sa0[2], sa0[3])),
                     fmaxf(fmaxf(sa1[0], sa1[1]), fmaxf(sa1[2], sa1[3])));
    const bool trig = __any(lm > m + 8.0f);
    if (trig) {
      float mx = fmaxf(lm, __shfl_xor(lm, 16));
      mx = fmaxf(mx, __shfl_xor(mx, 32));
      float mn = fmaxf(m, mx);
      float al = __expf(m - mn);
      m = mn;
      float alr[4];
#pragma unroll
      for (int r = 0; r < 4; ++r) alr[r] = __shfl(al, 4 * lq + r);
#pragma unroll
      for (int r = 0; r < 4; ++r) accl[r] *= alr[r];
      if (lq == 0) alsh[wave * 16 + l15] = al;
    }
    if (lane == 0) flg[wave] = trig ? 1 : 0;
    // ---- P = exp(S - m) packed f16, butterfly -> A-frag (R6-proven) ----
    int A0 = pk2(__expf(sa0[0] - m), __expf(sa0[1] - m));
    int A1 = pk2(__expf(sa0[2] - m), __expf(sa0[3] - m));
    int B0 = pk2(__expf(sa1[0] - m), __expf(sa1[1] - m));
    int B1 = pk2(__expf(sa1[2] - m), __expf(sa1[3] - m));
    const bool low = (lq < 2);
    int s0 = low ? B0 : A0, s1 = low ? B1 : A1;
    int X0 = __shfl_xor(s0, 32), X1 = __shfl_xor(s1, 32);
    int Y0 = low ? A0 : B0, Y1 = low ? A1 : B1;
    const bool sx = (lq == 0) || (lq == 3);
    int t0 = sx ? X0 : Y0, t1 = sx ? X1 : Y1;
    int Z0 = __shfl_xor(t0, 16), Z1 = __shfl_xor(t1, 16);
    union PU { int i[4]; f16x8 v; } pu;
    pu.i[0] = (lq == 0) ? Y0 : ((lq == 2) ? X0 : Z0);
    pu.i[1] = (lq == 0) ? Y1 : ((lq == 2) ? X1 : Z1);
    pu.i[2] = (lq == 1) ? X0 : ((lq == 3) ? Y0 : Z0);
    pu.i[3] = (lq == 1) ? X1 : ((lq == 3) ? Y1 : Z1);
    f16x8 pa = pu.v;
    accl = __builtin_amdgcn_mfma_f32_16x16x32_f16(pa, onef, accl, 0, 0, 0);
    *(f16x8*)&Pash[wave][lane * 8] = pa;
    // ---- barrier #1: LDS visibility only (DMA keeps flying) ----
    asm volatile("s_waitcnt lgkmcnt(0)" ::: "memory");
    __builtin_amdgcn_s_barrier();
    __builtin_amdgcn_sched_barrier(0);
    // ---- flags (uniform broadcast reads) ----
    int4 f0 = *(const int4*)&flg[0];
    int4 f4 = *(const int4*)&flg[4];
    const int fl[8] = {f0.x, f0.y, f0.z, f0.w, f4.x, f4.y, f4.z, f4.w};
    // ---- own-slice V fragments (reused across all 8 q-tiles) ----
    f16x8 vf[4];
#pragma unroll
    for (int j = 0; j < 4; ++j)
      vf[j] = *(const f16x8*)&Vl[buf][wave * 64 + j * 16 + l15][vs_off];
    // ---- per q-tile: rare rescale + PV ----
#pragma unroll
    for (int t = 0; t < 8; ++t) {
      if (fl[t]) {
        f32x4 alv = *(const f32x4*)&alsh[t * 16 + lq * 4];
#pragma unroll
        for (int j = 0; j < 4; ++j)
#pragma unroll
          for (int r = 0; r < 4; ++r) acco[t][j][r] *= alv[r];
      }
      f16x8 paT = *(const f16x8*)&Pash[t][lane * 8];
#pragma unroll
      for (int j = 0; j < 4; ++j)
        acco[t][j] = __builtin_amdgcn_mfma_f32_16x16x32_f16(paT, vf[j], acco[t][j], 0, 0, 0);
    }
    __syncthreads();  // #2: full drain; protects Pash/alsh/flg + K/V dbuf
  }
  // ---- epilogue: share 1/l via alsh, write own D-slice for all rows ----
  if (l15 == 0) {
    f32x4 iv = {1.0f / accl[0], 1.0f / accl[1], 1.0f / accl[2], 1.0f / accl[3]};
    *(f32x4*)&alsh[wave * 16 + lq * 4] = iv;
  }
  __syncthreads();
  const size_t ob = (size_t)(b * SS + qt * 128) * DD + wave * 64 + l15;
#pragma unroll
  for (int t = 0; t < 8; ++t) {
    f32x4 iv = *(const f32x4*)&alsh[t * 16 + lq * 4];
#pragma unroll
    for (int j = 0; j < 4; ++j)
#pragma unroll
      for (int r = 0; r < 4; ++r)
        out[ob + (size_t)(t * 16 + 4 * lq + r) * DD + j * 16] = acco[t][j][r] * iv[r];
  }
}

extern "C" void kernel_launch(void* const* d_in, const int* in_sizes, int n_in,
                              void* d_out, int out_size, void* d_ws, size_t ws_size,
                              hipStream_t stream) {
  const float* x = (const float*)d_in[0];
  const float* Wq = (const float*)d_in[1];
  const float* bq = (const float*)d_in[2];
  const float* Wk = (const float*)d_in[3];
  const float* bk = (const float*)d_in[4];
  const float* Wv = (const float*)d_in[5];
  const float* bv = (const float*)d_in[6];
  float* out = (float*)d_out;
  f16* ws = (f16*)d_ws;
  const size_t NX = (size_t)NB * SS * DD;  // 16,777,216
  f16* xh = ws;
  f16* Qh = ws + NX;
  f16* Kh = ws + 2 * NX;
  f16* Vth = ws + 3 * NX;
  f16* WqT = ws + 4 * NX;
  f16* WkT = WqT + DD * DD;
  f16* WvT = WkT + DD * DD;

  cast_kernel<<<NX / 8 / 256, 256, 0, stream>>>(x, xh);
  transpose_kernel<<<dim3(16, 16, 3), 256, 0, stream>>>(Wq, Wk, Wv, WqT, WkT, WvT);
  gemm3_kernel<<<3072, 256, 0, stream>>>(xh, WqT, WkT, WvT, Qh, Kh, Vth, bq, bk, bv);
  attn_kernel<<<256, 512, 0, stream>>>(Qh, Kh, Vth, out);
}

// Round 6
// 361.317 us; speedup vs baseline: 1.2190x; 1.2190x over previous
//
#include <hip/hip_runtime.h>
#include <math.h>

typedef _Float16 f16;
typedef _Float16 f16x2 __attribute__((ext_vector_type(2)));
typedef _Float16 f16x8 __attribute__((ext_vector_type(8)));
typedef float f32x4 __attribute__((ext_vector_type(4)));

#define NB 16
#define SS 2048
#define DD 512

// async global->LDS, 16B per lane; LDS dst = wave-uniform base + lane*16B
__device__ __forceinline__ void gl_lds16(const void* g, void* l) {
  __builtin_amdgcn_global_load_lds(
      (const __attribute__((address_space(1))) unsigned int*)g,
      (__attribute__((address_space(3))) unsigned int*)l, 16, 0, 0);
}

// pack two f32 -> f16x2 word
__device__ __forceinline__ int pk2(float a, float b) {
  f16x2 t = {(f16)a, (f16)b};
  return __builtin_bit_cast(int, t);
}

// ---------------- cast x (fp32) -> fp16, 8 elems/thread ----------------
__global__ __launch_bounds__(256) void cast_kernel(const float* __restrict__ x,
                                                   f16* __restrict__ o) {
  size_t i = (size_t)blockIdx.x * 256 + threadIdx.x;
  const float4* p = (const float4*)x + i * 2;
  float4 a = p[0], b = p[1];
  f16x8 v = {(f16)a.x, (f16)a.y, (f16)a.z, (f16)a.w,
             (f16)b.x, (f16)b.y, (f16)b.z, (f16)b.w};
  *((f16x8*)o + i) = v;
}

// ---------------- transpose 512x512 weights, fp32 -> fp16, z picks matrix ----
__global__ __launch_bounds__(256) void transpose_kernel(
    const float* __restrict__ W0, const float* __restrict__ W1,
    const float* __restrict__ W2, f16* __restrict__ T0, f16* __restrict__ T1,
    f16* __restrict__ T2) {
  const float* W = (blockIdx.z == 0) ? W0 : (blockIdx.z == 1) ? W1 : W2;
  f16* Wt = (blockIdx.z == 0) ? T0 : (blockIdx.z == 1) ? T1 : T2;
  __shared__ float t[32][33];
  int bx = blockIdx.x * 32, by = blockIdx.y * 32;
  int c = threadIdx.x & 31, r0 = threadIdx.x >> 5;
  for (int r = r0; r < 32; r += 8) t[r][c] = W[(size_t)(by + r) * DD + bx + c];
  __syncthreads();
  for (int r = r0; r < 32; r += 8) Wt[(size_t)(bx + r) * DD + by + c] = (f16)t[c][r];
}

// ---------------- fused QKV GEMM, R10: 256x256, 4-phase counted-vmcnt --------
// R8 post-mortem: 256^2 with __syncthreads (=vmcnt(0) drain of the ~250cyc-old
// prefetch) + 1 block/CU = exposed load latency every iter. R10 keeps R8's
// decode/swizzle/frags (harness-verified) and changes ONLY the schedule:
//  - full next-tile prefetch (8 DMA/thread) issued at phase 0 of iter kt
//  - vmcnt(0) deferred to END of phase 3 -> >=4 phases (~600+cyc) of cover;
//    tile-aligned drain = conservative, no cross-tile counting needed
//  - 4 sub-phases per K-tile (ks x mh quadrant: 16 MFMA, af[4] fresh, bf[4]
//    reused across mh), raw s_barrier per phase (no implicit vmcnt drain)
//  - T5 setprio(1) around each MFMA cluster (phase-split exists now)
// Buffer safety: stage writes buf^1; reads target buf; buf^1's last reader
// was iter kt-1 whose final barrier precedes this iter's stage. vmcnt(0)@ph3
// + barrier makes tile kt+1 globally visible before iter kt+1 reads it.
__global__ __launch_bounds__(512, 2) void gemmQKV_kernel(
    const f16* __restrict__ xh, const f16* __restrict__ WqT,
    const f16* __restrict__ WkT, const f16* __restrict__ WvT,
    f16* __restrict__ Qh, f16* __restrict__ Kh, f16* __restrict__ Vth,
    const float* __restrict__ bq, const float* __restrict__ bk,
    const float* __restrict__ bv) {
  const int wid = (blockIdx.x & 7) * 96 + (blockIdx.x >> 3);  // bijective XCD swz
  const f16* Wm;
  f16* C;
  const float* bias;
  size_t x0;            // first x-row staged (global, includes batch)
  size_t crow0, ccol0;  // output tile origin
  int w0, ldc, bias_row;
  float scale;
  bool isV;
  if (wid < 512) {  // Q (0..255) / K (256..511): C[32768][512] = xh * W^T
    const bool isK = wid >= 256;
    const int r = wid & 255;
    x0 = (size_t)(r >> 1) * 256;
    w0 = (r & 1) * 256;
    Wm = isK ? WkT : WqT;
    C = isK ? Kh : Qh;
    bias = isK ? bk : bq;
    crow0 = x0;
    ccol0 = (size_t)w0;
    ldc = DD;
    bias_row = 0;
    scale = isK ? 1.0f : 0.125f;  // fold 1/sqrt(64) into Q
    isV = false;
  } else {  // V^T per batch: Vt[512][2048] = WvT * x_b^T (operand-swap)
    const int v = wid - 512;
    const int b = v >> 4, e = (v >> 3) & 1, s = v & 7;
    x0 = (size_t)b * SS + (size_t)s * 256;
    w0 = e * 256;
    Wm = WvT;
    C = Vth + (size_t)b * DD * SS;
    bias = bv;
    crow0 = (size_t)w0;
    ccol0 = (size_t)s * 256;
    ldc = SS;
    bias_row = 1;
    scale = 1.0f;
    isV = true;
  }
  __shared__ f16 Xsh[2][256][64];
  __shared__ f16 Wsh[2][256][64];
  const int tid = threadIdx.x, lane = tid & 63, wave = tid >> 6;
  const int wm2 = wave >> 2, wn2 = wave & 3;
  const int l15 = lane & 15, lq = lane >> 4;
  const int srow = lane >> 3;          // staging: row within 8-row group
  const int sseg = (lane & 7) ^ srow;  // pre-swizzled source segment
  f32x4 acc[8][4] = {};
  auto stage = [&](int sb, int kt) {
#pragma unroll
    for (int g = 0; g < 4; ++g) {
      const int r0 = wave * 32 + g * 8;
      gl_lds16(xh + (x0 + r0 + srow) * DD + kt * 64 + sseg * 8,
               (f16*)&Xsh[sb][r0][0] + lane * 8);
      gl_lds16(Wm + (size_t)(w0 + r0 + srow) * DD + kt * 64 + sseg * 8,
               (f16*)&Wsh[sb][r0][0] + lane * 8);
    }
  };
  stage(0, 0);
  asm volatile("s_waitcnt vmcnt(0)" ::: "memory");
  asm volatile("s_barrier" ::: "memory");
  for (int kt = 0; kt < 8; ++kt) {
    const int buf = kt & 1;
    if (kt < 7) stage(buf ^ 1, kt + 1);  // 8 DMA; fly across all 4 phases
    const f16(*As)[64] = isV ? Wsh[buf] : Xsh[buf];
    const f16(*Bs)[64] = isV ? Xsh[buf] : Wsh[buf];
#pragma unroll
    for (int ks = 0; ks < 2; ++ks) {
      const int seg = ((ks * 4 + lq) ^ (l15 & 7)) * 8;
      f16x8 bf[4];
#pragma unroll
      for (int j = 0; j < 4; ++j)
        bf[j] = *(const f16x8*)&Bs[64 * wn2 + 16 * j + l15][seg];
#pragma unroll
      for (int mh = 0; mh < 2; ++mh) {
        f16x8 af[4];
#pragma unroll
        for (int i = 0; i < 4; ++i)
          af[i] = *(const f16x8*)&As[128 * wm2 + 64 * mh + 16 * i + l15][seg];
        __builtin_amdgcn_s_setprio(1);
#pragma unroll
        for (int i = 0; i < 4; ++i)
#pragma unroll
          for (int j = 0; j < 4; ++j)
            acc[4 * mh + i][j] = __builtin_amdgcn_mfma_f32_16x16x32_f16(
                af[i], bf[j], acc[4 * mh + i][j], 0, 0, 0);
        __builtin_amdgcn_s_setprio(0);
        if (ks == 1 && mh == 1)  // tile-aligned drain: tile kt+1 fully landed
          asm volatile("s_waitcnt vmcnt(0)" ::: "memory");
        asm volatile("s_barrier" ::: "memory");
      }
    }
  }
#pragma unroll
  for (int i = 0; i < 8; ++i) {
    const int arow = 128 * wm2 + 16 * i + 4 * lq;
#pragma unroll
    for (int j = 0; j < 4; ++j) {
      const int acol = 64 * wn2 + 16 * j + l15;
#pragma unroll
      for (int r = 0; r < 4; ++r) {
        const size_t rr = crow0 + arow + r;
        const size_t cc = ccol0 + acol;
        const float bvv = bias_row ? bias[rr] : bias[cc];
        C[rr * ldc + cc] = (f16)((acc[i][j][r] + bvv) * scale);
      }
    }
  }
}

// ---------------- flash attention, R6 (reverted: proven best 193us) ----------
// Swapped-QK, P fully in-register, wave-independent softmax, ONE barrier/iter.
__global__ __launch_bounds__(512, 2) void attn_kernel(
    const f16* __restrict__ Q, const f16* __restrict__ K,
    const f16* __restrict__ Vt, float* __restrict__ out) {
  const int id = blockIdx.x;
  const int b = (id & 7) + ((id >> 7) << 3);  // XCD x gets batches {x, x+8}
  const int qt = (id >> 3) & 15;
  const int tid = threadIdx.x, lane = tid & 63, wave = tid >> 6;
  const int l15 = lane & 15, lq = lane >> 4;

  __shared__ __align__(16) f16 Kl[2][32][520];  // [key][d], 1040B rows
  __shared__ __align__(16) f16 Vl[2][512][32];  // [e][key], XOR-swizzled quarters

  const f16* qp = Q + ((size_t)(b * SS + qt * 128 + wave * 16 + l15)) * DD + lq * 8;
  f16x8 qf[16];
#pragma unroll
  for (int kk = 0; kk < 16; ++kk) qf[kk] = *(const f16x8*)(qp + kk * 32);

  const f16* Kb = K + (size_t)b * SS * DD;   // [key][d]
  const f16* Vb = Vt + (size_t)b * DD * SS;  // [e][s]

  const int sdata = (lane & 3) ^ ((lane >> 3) & 3);
  const int vrow = lane >> 2;
  const int vs_off = (lq ^ ((l15 >> 1) & 3)) * 8;

  f16x8 onef;
#pragma unroll
  for (int j = 0; j < 8; ++j) onef[j] = (f16)1.0f;

  auto stage = [&](int sb, int kb) {
#pragma unroll
    for (int rr = 0; rr < 4; ++rr) {
      int row = wave * 4 + rr;
      gl_lds16(Kb + ((size_t)(kb + row)) * DD + lane * 8, &Kl[sb][row][lane * 8]);
    }
#pragma unroll
    for (int i = 0; i < 4; ++i) {
      int e0 = wave * 64 + i * 16;
      gl_lds16(Vb + (size_t)(e0 + vrow) * SS + kb + sdata * 8,
               (f16*)&Vl[sb][e0][0] + lane * 8);
    }
  };

  stage(0, 0);
  __syncthreads();

  f32x4 acco[32] = {};
  f32x4 accl = {};
  float m = -1e30f;

  for (int it = 0; it < 64; ++it) {
    const int buf = it & 1;
    if (it < 63) stage(buf ^ 1, (it + 1) * 32);
    f32x4 sa0 = {}, sa1 = {};
#pragma unroll
    for (int kk = 0; kk < 16; ++kk) {
      f16x8 b0 = *(const f16x8*)&Kl[buf][l15][kk * 32 + lq * 8];
      f16x8 b1 = *(const f16x8*)&Kl[buf][16 + l15][kk * 32 + lq * 8];
      sa0 = __builtin_amdgcn_mfma_f32_16x16x32_f16(b0, qf[kk], sa0, 0, 0, 0);
      sa1 = __builtin_amdgcn_mfma_f32_16x16x32_f16(b1, qf[kk], sa1, 0, 0, 0);
    }
    float lm = fmaxf(fmaxf(fmaxf(sa0[0], sa0[1]), fmaxf(sa0[2], sa0[3])),
                     fmaxf(fmaxf(sa1[0], sa1[1]), fmaxf(sa1[2], sa1[3])));
    if (__any(lm > m + 8.0f)) {
      float mx = lm;
      mx = fmaxf(mx, __shfl_xor(mx, 16));
      mx = fmaxf(mx, __shfl_xor(mx, 32));
      float mn = fmaxf(m, mx);
      float al = __expf(m - mn);
      m = mn;
      float alr[4];
#pragma unroll
      for (int r = 0; r < 4; ++r) alr[r] = __shfl(al, 4 * lq + r);
#pragma unroll
      for (int t = 0; t < 32; ++t)
#pragma unroll
        for (int r = 0; r < 4; ++r) acco[t][r] *= alr[r];
#pragma unroll
      for (int r = 0; r < 4; ++r) accl[r] *= alr[r];
    }
    int A0 = pk2(__expf(sa0[0] - m), __expf(sa0[1] - m));
    int A1 = pk2(__expf(sa0[2] - m), __expf(sa0[3] - m));
    int B0 = pk2(__expf(sa1[0] - m), __expf(sa1[1] - m));
    int B1 = pk2(__expf(sa1[2] - m), __expf(sa1[3] - m));
    const bool low = (lq < 2);
    int s0 = low ? B0 : A0, s1 = low ? B1 : A1;
    int X0 = __shfl_xor(s0, 32), X1 = __shfl_xor(s1, 32);
    int Y0 = low ? A0 : B0, Y1 = low ? A1 : B1;
    const bool sx = (lq == 0) || (lq == 3);
    int t0 = sx ? X0 : Y0, t1 = sx ? X1 : Y1;
    int Z0 = __shfl_xor(t0, 16), Z1 = __shfl_xor(t1, 16);
    union PU { int i[4]; f16x8 v; } pu;
    pu.i[0] = (lq == 0) ? Y0 : ((lq == 2) ? X0 : Z0);
    pu.i[1] = (lq == 0) ? Y1 : ((lq == 2) ? X1 : Z1);
    pu.i[2] = (lq == 1) ? X0 : ((lq == 3) ? Y0 : Z0);
    pu.i[3] = (lq == 1) ? X1 : ((lq == 3) ? Y1 : Z1);
    f16x8 pa = pu.v;
    accl = __builtin_amdgcn_mfma_f32_16x16x32_f16(pa, onef, accl, 0, 0, 0);
#pragma unroll
    for (int nn = 0; nn < 32; ++nn) {
      f16x8 vf = *(const f16x8*)&Vl[buf][nn * 16 + l15][vs_off];
      acco[nn] = __builtin_amdgcn_mfma_f32_16x16x32_f16(pa, vf, acco[nn], 0, 0, 0);
    }
    __syncthreads();
  }
  float inv[4];
#pragma unroll
  for (int r = 0; r < 4; ++r) inv[r] = 1.0f / accl[r];
  const size_t ob = ((size_t)(b * SS + qt * 128 + wave * 16 + 4 * lq)) * DD + l15;
#pragma unroll
  for (int nn = 0; nn < 32; ++nn)
#pragma unroll
    for (int r = 0; r < 4; ++r)
      out[ob + (size_t)r * DD + nn * 16] = acco[nn][r] * inv[r];
}

extern "C" void kernel_launch(void* const* d_in, const int* in_sizes, int n_in,
                              void* d_out, int out_size, void* d_ws, size_t ws_size,
                              hipStream_t stream) {
  const float* x = (const float*)d_in[0];
  const float* Wq = (const float*)d_in[1];
  const float* bq = (const float*)d_in[2];
  const float* Wk = (const float*)d_in[3];
  const float* bk = (const float*)d_in[4];
  const float* Wv = (const float*)d_in[5];
  const float* bv = (const float*)d_in[6];
  float* out = (float*)d_out;
  f16* ws = (f16*)d_ws;
  const size_t NX = (size_t)NB * SS * DD;  // 16,777,216
  f16* xh = ws;
  f16* Qh = ws + NX;
  f16* Kh = ws + 2 * NX;
  f16* Vth = ws + 3 * NX;
  f16* WqT = ws + 4 * NX;
  f16* WkT = WqT + DD * DD;
  f16* WvT = WkT + DD * DD;

  cast_kernel<<<NX / 8 / 256, 256, 0, stream>>>(x, xh);
  transpose_kernel<<<dim3(16, 16, 3), 256, 0, stream>>>(Wq, Wk, Wv, WqT, WkT, WvT);
  gemmQKV_kernel<<<768, 512, 0, stream>>>(xh, WqT, WkT, WvT, Qh, Kh, Vth, bq, bk, bv);
  attn_kernel<<<256, 512, 0, stream>>>(Qh, Kh, Vth, out);
}